// Round 3
// baseline (17.792 us; speedup 1.0000x reference)
//
#include <hip/hip_runtime.h>
#include <hip/hip_bf16.h>

// MeanSpanRepr via chunked prefix sums, 2 kernels.
// S[b,t,:] = chunk-local inclusive prefix of x[b,:,:] (chunk = 32 rows).
// Tot[b,c,:] = total of chunk c. Query kernel reconstructs global prefix:
// P[t] = S[t] + sum_{c < t/32} Tot[c]  (Tot sum done on the fly, L2-hot).
// out[q,:] = (P[end] - P[start-1]) / len.
// B=32, T=512, D=256, Q=2048.

constexpr int kB  = 32;
constexpr int kT  = 512;
constexpr int kD  = 256;
constexpr int kD4 = kD / 4;     // 64 float4 per row
constexpr int kCL = 32;         // chunk length (t rows)
constexpr int kNC = kT / kCL;   // 16 chunks
constexpr int kSub = 8;         // rows per t-subgroup (4 subgroups of 8)

// ---------- kernel A: chunk-local inclusive scan (float4, register scan) ----------
__global__ __launch_bounds__(256) void scan_chunk_v2(
    const float4* __restrict__ x4, float4* __restrict__ S4,
    float4* __restrict__ Tot4) {
    const int blk  = blockIdx.x;        // b*kNC + c
    const int b    = blk >> 4;
    const int c    = blk & (kNC - 1);
    const int lane = threadIdx.x & 63;  // d4 column
    const int sub  = threadIdx.x >> 6;  // t-subgroup [0,4)

    const size_t base =
        ((size_t)b * kT + (size_t)c * kCL + (size_t)sub * kSub) * kD4 + lane;

    float4 v[kSub];
#pragma unroll
    for (int i = 0; i < kSub; ++i) v[i] = x4[base + (size_t)i * kD4];
#pragma unroll
    for (int i = 1; i < kSub; ++i) {
        v[i].x += v[i-1].x; v[i].y += v[i-1].y;
        v[i].z += v[i-1].z; v[i].w += v[i-1].w;
    }

    __shared__ float4 st[4][64];
    st[sub][lane] = v[kSub-1];
    __syncthreads();

    float4 off = make_float4(0.f, 0.f, 0.f, 0.f);
    for (int s2 = 0; s2 < sub; ++s2) {   // sub is wave-uniform; <=3 iters
        float4 t = st[s2][lane];
        off.x += t.x; off.y += t.y; off.z += t.z; off.w += t.w;
    }

#pragma unroll
    for (int i = 0; i < kSub; ++i) {
        v[i].x += off.x; v[i].y += off.y; v[i].z += off.z; v[i].w += off.w;
        S4[base + (size_t)i * kD4] = v[i];
    }
    if (sub == 3)
        Tot4[((size_t)b * kNC + c) * kD4 + lane] = v[kSub-1];  // chunk total
}

// ---------- kernel C: per-query span mean (on-the-fly chunk offsets) ----------
__global__ __launch_bounds__(256) void span_from_prefix_v2(
    const float4* __restrict__ S4, const float4* __restrict__ Tot4,
    const int* __restrict__ start_ids, const int* __restrict__ end_ids,
    const int* __restrict__ batch_ids, float4* __restrict__ out4, int Q) {
    const int q = blockIdx.x * 4 + (threadIdx.x >> 6);  // one wave per query
    if (q >= Q) return;
    const int lane = threadIdx.x & 63;

    const int s = start_ids[q];
    const int e = end_ids[q];
    const int b = batch_ids[q];
    const int p  = s - 1;            // valid iff s > 0
    const int ce = e >> 5;           // end chunk
    const int cp = (s > 0) ? (p >> 5) : 0;

    const size_t sbase = (size_t)b * kT * kD4 + lane;
    const size_t tbase = (size_t)b * kNC * kD4 + lane;

    // acc = sum_{c<ce} Tot[c]; lo_off = sum_{c<cp} Tot[c] (cp <= ce)
    float4 acc    = make_float4(0.f, 0.f, 0.f, 0.f);
    float4 lo_off = make_float4(0.f, 0.f, 0.f, 0.f);
    for (int c = 0; c < ce; ++c) {   // wave-uniform bound, <=15 iters
        if (s > 0 && c == cp) lo_off = acc;
        float4 t = Tot4[tbase + (size_t)c * kD4];
        acc.x += t.x; acc.y += t.y; acc.z += t.z; acc.w += t.w;
    }
    if (s > 0 && cp == ce) lo_off = acc;

    float4 hi = S4[sbase + (size_t)e * kD4];
    float sx = hi.x + acc.x, sy = hi.y + acc.y;
    float sz = hi.z + acc.z, sw = hi.w + acc.w;

    if (s > 0) {
        float4 lo = S4[sbase + (size_t)p * kD4];
        sx -= lo.x + lo_off.x; sy -= lo.y + lo_off.y;
        sz -= lo.z + lo_off.z; sw -= lo.w + lo_off.w;
    }

    const float inv = 1.0f / (float)(e - s + 1);
    float4 r;
    r.x = sx * inv; r.y = sy * inv; r.z = sz * inv; r.w = sw * inv;
    out4[(size_t)q * kD4 + lane] = r;
}

// ---------- fallback: direct gather ----------
__global__ __launch_bounds__(256) void span_mean_direct_kernel(
    const float* __restrict__ x,
    const int* __restrict__ start_ids, const int* __restrict__ end_ids,
    const int* __restrict__ batch_ids, float* __restrict__ out) {
    const int q   = blockIdx.x;
    const int tid = threadIdx.x;
    const int c   = tid & 63;
    const int tr  = tid >> 6;

    const int st = start_ids[q];
    const int en = end_ids[q];
    const int b  = batch_ids[q];
    const int len = en - st + 1;

    const float4* __restrict__ row_base =
        reinterpret_cast<const float4*>(x + (size_t)b * kT * kD) + c;

    float4 acc = make_float4(0.f, 0.f, 0.f, 0.f);
    for (int t = st + tr; t <= en; t += 4) {
        float4 v = row_base[(size_t)t * kD4];
        acc.x += v.x; acc.y += v.y; acc.z += v.z; acc.w += v.w;
    }

    __shared__ float4 red[256];
    red[tid] = acc;
    __syncthreads();

    if (tr == 0) {
        float4 a0 = red[c], a1 = red[64 + c], a2 = red[128 + c], a3 = red[192 + c];
        const float inv = 1.0f / (float)len;
        float4 r;
        r.x = (a0.x + a1.x + a2.x + a3.x) * inv;
        r.y = (a0.y + a1.y + a2.y + a3.y) * inv;
        r.z = (a0.z + a1.z + a2.z + a3.z) * inv;
        r.w = (a0.w + a1.w + a2.w + a3.w) * inv;
        reinterpret_cast<float4*>(out)[(size_t)q * kD4 + c] = r;
    }
}

extern "C" void kernel_launch(void* const* d_in, const int* in_sizes, int n_in,
                              void* d_out, int out_size, void* d_ws, size_t ws_size,
                              hipStream_t stream) {
    const float* x        = (const float*)d_in[0];
    const int* start_ids  = (const int*)d_in[1];
    const int* end_ids    = (const int*)d_in[2];
    const int* batch_ids  = (const int*)d_in[3];
    float* out            = (float*)d_out;
    const int Q = in_sizes[1];  // 2048

    const size_t bytesS   = (size_t)kB * kT * kD * sizeof(float);   // 16 MB
    const size_t bytesTot = (size_t)kB * kNC * kD * sizeof(float);  // 512 KB
    const size_t need     = bytesS + bytesTot;

    if (ws_size < need) {
        span_mean_direct_kernel<<<Q, 256, 0, stream>>>(x, start_ids, end_ids, batch_ids, out);
        return;
    }

    float4* S4   = (float4*)d_ws;
    float4* Tot4 = (float4*)((char*)d_ws + bytesS);

    scan_chunk_v2<<<kB * kNC, 256, 0, stream>>>((const float4*)x, S4, Tot4);
    span_from_prefix_v2<<<(Q + 3) / 4, 256, 0, stream>>>(
        S4, Tot4, start_ids, end_ids, batch_ids, (float4*)out, Q);
}

// Round 4
// 15.830 us; speedup vs baseline: 1.1239x; 1.1239x over previous
//
#include <hip/hip_runtime.h>
#include <hip/hip_bf16.h>

// MeanSpanRepr, fully fused single kernel.
// Block (b, dt) owns batch b and a 16-float d-slice. It builds the inclusive
// prefix P[t] of x[b, :, dslice] in LDS (register chunk scan + shfl_up wave
// scan + cross-wave combine), stages query metadata in LDS, then answers
// every query with batch==b in O(1): out = (P[e] - P[s-1]) / len.
// B=32, T=512, D=256, Q=2048. HBM: read x once (16MB) + write out (2MB).

constexpr int kB    = 32;
constexpr int kT    = 512;
constexpr int kD    = 256;
constexpr int kD4   = kD / 4;   // 64 float4 per full row
constexpr int kDT4  = 4;        // float4 per tile row (16 floats)
constexpr int kNDT  = kD4 / kDT4; // 16 d-tiles
constexpr int kRows = 8;        // t-rows per thread chunk
constexpr int kRS   = 5;        // LDS row stride in float4 (80B, breaks pow2)
constexpr int kQmax = 2048;

__device__ inline float4 f4add(float4 a, float4 b) {
    return make_float4(a.x + b.x, a.y + b.y, a.z + b.z, a.w + b.w);
}

__global__ __launch_bounds__(256) void fused_span_mean(
    const float4* __restrict__ x4,
    const int* __restrict__ start_ids, const int* __restrict__ end_ids,
    const int* __restrict__ batch_ids, float4* __restrict__ out4, int Q) {

    __shared__ float4 P[kT * kRS];           // 40 KB prefix tile
    __shared__ float4 wtot[4][kDT4];         // per-wave inclusive totals
    __shared__ int sm_s[kQmax], sm_e[kQmax], sm_b[kQmax];  // 24 KB metadata

    const int b   = blockIdx.x >> 4;
    const int dt  = blockIdx.x & (kNDT - 1);
    const int tid = threadIdx.x;
    const int d4  = tid & 3;                 // float4 column within tile
    const int tc  = tid >> 2;                // chunk id [0,64)
    const int w   = tid >> 6;                // wave id [0,4)
    const int lw  = tid & 63;                // lane in wave

    // ---- stage query metadata (coalesced) ----
    for (int k = 0; k < kQmax / 256; ++k) {
        const int idx = tid + k * 256;
        if (idx < Q) {
            sm_s[idx] = start_ids[idx];
            sm_e[idx] = end_ids[idx];
            sm_b[idx] = batch_ids[idx];
        }
    }

    // ---- load 8 rows, chunk-local inclusive scan in registers ----
    const size_t gbase = ((size_t)b * kT + (size_t)tc * kRows) * kD4
                       + (size_t)dt * kDT4 + d4;
    float4 v[kRows];
    float4 acc = make_float4(0.f, 0.f, 0.f, 0.f);
#pragma unroll
    for (int i = 0; i < kRows; ++i) {
        acc = f4add(acc, x4[gbase + (size_t)i * kD4]);
        v[i] = acc;
    }
    const float4 ctot = acc;  // this chunk's total

    // ---- wave-level inclusive scan over the 16 chunks (stride 4 lanes) ----
    float4 run = ctot;
#pragma unroll
    for (int off = 4; off < 64; off <<= 1) {
        float4 o;
        o.x = __shfl_up(run.x, off);
        o.y = __shfl_up(run.y, off);
        o.z = __shfl_up(run.z, off);
        o.w = __shfl_up(run.w, off);
        if (lw >= off) run = f4add(run, o);
    }
    // exclusive offset within this wave's 128-row span
    float4 excl = make_float4(run.x - ctot.x, run.y - ctot.y,
                              run.z - ctot.z, run.w - ctot.w);

    if ((lw >> 2) == 15) wtot[w][d4] = run;  // wave's inclusive total per d4
    __syncthreads();                         // wtot + metadata visible

    float4 woff = make_float4(0.f, 0.f, 0.f, 0.f);
    for (int w2 = 0; w2 < w; ++w2)           // <=3 iters, wave-uniform
        woff = f4add(woff, wtot[w2][d4]);

    const float4 off4 = f4add(woff, excl);
#pragma unroll
    for (int i = 0; i < kRows; ++i) {
        const int t = tc * kRows + i;
        P[t * kRS + d4] = f4add(v[i], off4);
    }
    __syncthreads();                         // P complete

    // ---- query phase: 4 threads per query, 64 query-groups ----
    const int g = tc;                        // group id [0,64)
    for (int q = g; q < Q; q += 64) {
        if (sm_b[q] != b) continue;
        const int s = sm_s[q];
        const int e = sm_e[q];
        const float4 hi = P[e * kRS + d4];
        float4 lo = make_float4(0.f, 0.f, 0.f, 0.f);
        if (s > 0) lo = P[(s - 1) * kRS + d4];
        const float inv = 1.0f / (float)(e - s + 1);
        float4 r;
        r.x = (hi.x - lo.x) * inv;
        r.y = (hi.y - lo.y) * inv;
        r.z = (hi.z - lo.z) * inv;
        r.w = (hi.w - lo.w) * inv;
        out4[(size_t)q * kD4 + dt * kDT4 + d4] = r;
    }
}

// ---------- fallback: direct gather (known-good, ~34 us) ----------
__global__ __launch_bounds__(256) void span_mean_direct_kernel(
    const float* __restrict__ x,
    const int* __restrict__ start_ids, const int* __restrict__ end_ids,
    const int* __restrict__ batch_ids, float* __restrict__ out) {
    const int q   = blockIdx.x;
    const int tid = threadIdx.x;
    const int c   = tid & 63;
    const int tr  = tid >> 6;

    const int st = start_ids[q];
    const int en = end_ids[q];
    const int b  = batch_ids[q];
    const int len = en - st + 1;

    const float4* __restrict__ row_base =
        reinterpret_cast<const float4*>(x + (size_t)b * kT * kD) + c;

    float4 acc = make_float4(0.f, 0.f, 0.f, 0.f);
    for (int t = st + tr; t <= en; t += 4) {
        float4 v = row_base[(size_t)t * kD4];
        acc.x += v.x; acc.y += v.y; acc.z += v.z; acc.w += v.w;
    }

    __shared__ float4 red[256];
    red[tid] = acc;
    __syncthreads();

    if (tr == 0) {
        float4 a0 = red[c], a1 = red[64 + c], a2 = red[128 + c], a3 = red[192 + c];
        const float inv = 1.0f / (float)len;
        float4 r;
        r.x = (a0.x + a1.x + a2.x + a3.x) * inv;
        r.y = (a0.y + a1.y + a2.y + a3.y) * inv;
        r.z = (a0.z + a1.z + a2.z + a3.z) * inv;
        r.w = (a0.w + a1.w + a2.w + a3.w) * inv;
        reinterpret_cast<float4*>(out)[(size_t)q * kD4 + c] = r;
    }
}

extern "C" void kernel_launch(void* const* d_in, const int* in_sizes, int n_in,
                              void* d_out, int out_size, void* d_ws, size_t ws_size,
                              hipStream_t stream) {
    const float* x        = (const float*)d_in[0];
    const int* start_ids  = (const int*)d_in[1];
    const int* end_ids    = (const int*)d_in[2];
    const int* batch_ids  = (const int*)d_in[3];
    float* out            = (float*)d_out;
    const int Q = in_sizes[1];  // 2048

    if (in_sizes[0] != kB * kT * kD || Q > kQmax) {
        // unexpected shape: known-good direct gather
        span_mean_direct_kernel<<<Q, 256, 0, stream>>>(x, start_ids, end_ids, batch_ids, out);
        return;
    }

    fused_span_mean<<<kB * kNDT, 256, 0, stream>>>(
        (const float4*)x, start_ids, end_ids, batch_ids, (float4*)out, Q);
}

// Round 5
// 11.890 us; speedup vs baseline: 1.4963x; 1.3314x over previous
//
#include <hip/hip_runtime.h>
#include <hip/hip_bf16.h>

// MeanSpanRepr, fused single kernel, v2 geometry.
// Block (b, sl) owns batch b and an 8-float4 (32-float) d-slice. 512 threads:
// lane layout d4 = tid&7 (covers a full 128B line per row), tc = tid>>3
// (64 chunks of 8 t-rows). Register chunk-scan -> shfl_up wave scan over
// chunks -> cross-wave LDS combine -> prefix table P[512][8] float4 in LDS.
// Query metadata packed (b<<18 | s<<9 | e) into 8 KB LDS. Each 8-lane group
// answers queries q = g, g+64, ... with batch==b in O(1) from P.
// HBM: x read once (16 MB) + out write (2 MB) + metadata (L2-hot).
// B=32, T=512, D=256, Q=2048.

constexpr int kB    = 32;
constexpr int kT    = 512;
constexpr int kD    = 256;
constexpr int kD4   = kD / 4;     // 64 float4 per full row
constexpr int kSL   = 8;          // float4 per slice row (32 floats, 128B)
constexpr int kNSL  = kD4 / kSL;  // 8 d-slices
constexpr int kRows = 8;          // t-rows per chunk
constexpr int kQmax = 2048;

__device__ inline float4 f4add(float4 a, float4 b) {
    return make_float4(a.x + b.x, a.y + b.y, a.z + b.z, a.w + b.w);
}

__global__ __launch_bounds__(512) void fused_span_mean_v2(
    const float4* __restrict__ x4,
    const int* __restrict__ start_ids, const int* __restrict__ end_ids,
    const int* __restrict__ batch_ids, float4* __restrict__ out4, int Q) {

    __shared__ float4 P[kT * kSL];        // 64 KB prefix tile (128B row stride)
    __shared__ float4 wtot[8][kSL];       // per-wave totals, 1 KB
    __shared__ unsigned sm[kQmax];        // packed metadata, 8 KB

    const int b   = blockIdx.x >> 3;      // batch
    const int sl  = blockIdx.x & (kNSL - 1);
    const int tid = threadIdx.x;
    const int d4  = tid & 7;              // float4 column in slice
    const int tc  = tid >> 3;             // chunk id [0,64)
    const int w   = tid >> 6;             // wave id [0,8)
    const int lw  = tid & 63;             // lane in wave

    // ---- stage packed query metadata (coalesced, 4 iters) ----
    for (int k = tid; k < Q; k += 512) {
        sm[k] = ((unsigned)batch_ids[k] << 18) |
                ((unsigned)start_ids[k] << 9)  |
                 (unsigned)end_ids[k];
    }

    // ---- load 8 rows (128B-coalesced), chunk-local inclusive scan ----
    const size_t gbase = ((size_t)b * kT + (size_t)tc * kRows) * kD4
                       + (size_t)sl * kSL + d4;
    float4 v[kRows];
    float4 acc = make_float4(0.f, 0.f, 0.f, 0.f);
#pragma unroll
    for (int i = 0; i < kRows; ++i) {
        acc = f4add(acc, x4[gbase + (size_t)i * kD4]);
        v[i] = acc;
    }

    // ---- wave-level inclusive scan over 8 chunks (stride-8 lanes) ----
    float4 run = acc;
#pragma unroll
    for (int off = 8; off < 64; off <<= 1) {
        float4 o;
        o.x = __shfl_up(run.x, off);
        o.y = __shfl_up(run.y, off);
        o.z = __shfl_up(run.z, off);
        o.w = __shfl_up(run.w, off);
        if (lw >= off) run = f4add(run, o);
    }
    const float4 excl = make_float4(run.x - acc.x, run.y - acc.y,
                                    run.z - acc.z, run.w - acc.w);

    if ((lw >> 3) == 7) wtot[w][d4] = run;   // wave's inclusive total
    __syncthreads();                          // wtot + sm visible

    float4 woff = make_float4(0.f, 0.f, 0.f, 0.f);
    for (int w2 = 0; w2 < w; ++w2)            // wave-uniform, <=7 iters
        woff = f4add(woff, wtot[w2][d4]);

    const float4 off4 = f4add(woff, excl);
#pragma unroll
    for (int i = 0; i < kRows; ++i)
        P[(tc * kRows + i) * kSL + d4] = f4add(v[i], off4);
    __syncthreads();                          // P complete

    // ---- query phase: 8 lanes per query, 64 groups ----
    for (int q = tc; q < Q; q += 64) {
        const unsigned pk = sm[q];
        if ((int)(pk >> 18) != b) continue;
        const int e = (int)(pk & 511u);
        const int s = (int)((pk >> 9) & 511u);
        const float4 hi = P[e * kSL + d4];
        float4 lo = make_float4(0.f, 0.f, 0.f, 0.f);
        if (s > 0) lo = P[(s - 1) * kSL + d4];
        const float inv = 1.0f / (float)(e - s + 1);
        float4 r;
        r.x = (hi.x - lo.x) * inv;
        r.y = (hi.y - lo.y) * inv;
        r.z = (hi.z - lo.z) * inv;
        r.w = (hi.w - lo.w) * inv;
        out4[(size_t)q * kD4 + sl * kSL + d4] = r;  // 128B-coalesced per group
    }
}

// ---------- fallback: direct gather (known-good, ~34 us) ----------
__global__ __launch_bounds__(256) void span_mean_direct_kernel(
    const float* __restrict__ x,
    const int* __restrict__ start_ids, const int* __restrict__ end_ids,
    const int* __restrict__ batch_ids, float* __restrict__ out) {
    const int q   = blockIdx.x;
    const int tid = threadIdx.x;
    const int c   = tid & 63;
    const int tr  = tid >> 6;

    const int st = start_ids[q];
    const int en = end_ids[q];
    const int b  = batch_ids[q];
    const int len = en - st + 1;

    const float4* __restrict__ row_base =
        reinterpret_cast<const float4*>(x + (size_t)b * kT * kD) + c;

    float4 acc = make_float4(0.f, 0.f, 0.f, 0.f);
    for (int t = st + tr; t <= en; t += 4) {
        float4 vv = row_base[(size_t)t * kD4];
        acc.x += vv.x; acc.y += vv.y; acc.z += vv.z; acc.w += vv.w;
    }

    __shared__ float4 red[256];
    red[tid] = acc;
    __syncthreads();

    if (tr == 0) {
        float4 a0 = red[c], a1 = red[64 + c], a2 = red[128 + c], a3 = red[192 + c];
        const float inv = 1.0f / (float)len;
        float4 r;
        r.x = (a0.x + a1.x + a2.x + a3.x) * inv;
        r.y = (a0.y + a1.y + a2.y + a3.y) * inv;
        r.z = (a0.z + a1.z + a2.z + a3.z) * inv;
        r.w = (a0.w + a1.w + a2.w + a3.w) * inv;
        reinterpret_cast<float4*>(out)[(size_t)q * kD4 + c] = r;
    }
}

extern "C" void kernel_launch(void* const* d_in, const int* in_sizes, int n_in,
                              void* d_out, int out_size, void* d_ws, size_t ws_size,
                              hipStream_t stream) {
    const float* x        = (const float*)d_in[0];
    const int* start_ids  = (const int*)d_in[1];
    const int* end_ids    = (const int*)d_in[2];
    const int* batch_ids  = (const int*)d_in[3];
    float* out            = (float*)d_out;
    const int Q = in_sizes[1];  // 2048

    if (in_sizes[0] != kB * kT * kD || Q > kQmax) {
        span_mean_direct_kernel<<<Q, 256, 0, stream>>>(x, start_ids, end_ids, batch_ids, out);
        return;
    }

    fused_span_mean_v2<<<kB * kNSL, 512, 0, stream>>>(
        (const float4*)x, start_ids, end_ids, batch_ids, (float4*)out, Q);
}